// Round 8
// baseline (12107.955 us; speedup 1.0000x reference)
//
#include <hip/hip_runtime.h>

#define B_ 128
#define S_ 4096
#define IN_ 6
#define N_ 64
#define MOT_ 3
#define UNF 6
#define EPS_ 1e-8f
#define LOG2E 1.4426950408889634f

// ---- VALU-pipe cross-lane pair-sums over lane bits 4 and 5 ----
__device__ __forceinline__ float red16(float x) {
#if __has_builtin(__builtin_amdgcn_permlane16_swap)
    auto r = __builtin_amdgcn_permlane16_swap(__float_as_int(x), __float_as_int(x),
                                              false, false);
    return __int_as_float((int)r[0]) + __int_as_float((int)r[1]);
#else
    return x + __shfl_xor(x, 16, 64);
#endif
}
__device__ __forceinline__ float red32(float x) {
#if __has_builtin(__builtin_amdgcn_permlane32_swap)
    auto r = __builtin_amdgcn_permlane32_swap(__float_as_int(x), __float_as_int(x),
                                              false, false);
    return __int_as_float((int)r[0]) + __int_as_float((int)r[1]);
#else
    return x + __shfl_xor(x, 32, 64);
#endif
}

// One workgroup per batch chain. 256 threads = 4 waves = 1 wave/SIMD.
// NO s_barrier in the main loop: dataflow sync via per-wave monotonic LDS
// flags. Wave w owns columns w*16..w*16+15. Lane l = (cc=l>>4, ii=l&15),
// column myCol = 16w+ii, j-set {16q + 4cc + r : q,r in 0..3} so the v's
// needed from wave q are ONE aligned float4 of vbuf. Per unfold: spin on 4
// flags (usually already set), 4x ds_read_b128, 16 sigmoids, 2-stage VALU
// butterfly over cc, update, 16-lane v-write, lgkmcnt(0), lane-0 flag store.
// Wave skew is bounded to 1 unfold by the data dependency itself, so 2
// v-buffers and step-parity sensory buffers are race-free.
__launch_bounds__(256, 1)
__global__ void ltc_kernel(
    const float* __restrict__ x,
    const float* __restrict__ mean_us, const float* __restrict__ std_us,
    const float* __restrict__ input_w, const float* __restrict__ input_b,
    const float* __restrict__ output_w, const float* __restrict__ output_b,
    const float* __restrict__ gleak, const float* __restrict__ vleak,
    const float* __restrict__ cm,
    const float* __restrict__ sW, const float* __restrict__ sMu,
    const float* __restrict__ sSig, const float* __restrict__ sErev,
    const float* __restrict__ W, const float* __restrict__ Mu,
    const float* __restrict__ Sig, const float* __restrict__ Erev,
    float* __restrict__ out)
{
    const int b    = blockIdx.x;
    const int t    = threadIdx.x;
    const int lane = t & 63;
    const int w    = t >> 6;      // wave 0..3
    const int cc   = lane >> 4;   // 0..3
    const int ii   = lane & 15;
    const int myCol = w * 16 + ii;
    const int cc4  = cc * 4;

    __shared__ __align__(16) float vbuf[2][N_];
    __shared__ int vflag[2][4];               // [parity][producer wave]
    __shared__ float s_lds[2][IN_][N_][2];    // [step parity][in][col][{n,d}]

    // --- recurrent synapse params: j = 16q + 4cc + r, column myCol ---
    // sigmoid((v-mu)*sig) = 1/(1+exp2(v*A + Bc)), A=-sig*log2e, Bc=mu*sig*log2e
    float A[16], Bc[16], Wr[16], We[16];
#pragma unroll
    for (int q = 0; q < 4; ++q) {
#pragma unroll
        for (int r = 0; r < 4; ++r) {
            int j   = q * 16 + cc4 + r;
            int idx = j * N_ + myCol;
            float sg = Sig[idx], m = Mu[idx], ww = W[idx], e = Erev[idx];
            A[q*4+r]  = -sg * LOG2E;
            Bc[q*4+r] = m * sg * LOG2E;
            Wr[q*4+r] = ww;
            We[q*4+r] = ww * e;
        }
    }

    // --- per-column state consts ---
    const float cmt = cm[myCol] * (float)UNF;
    const float glk = gleak[myCol];
    const float gv  = glk * vleak[myCol];
    const float dbase = cmt + glk + EPS_;

    // --- sensory params: wave w handles input w; waves 0,1 also input w+4 ---
    const int i0 = w;
    const int i1 = w + 4;
    const bool has1 = (w < 2);
    float SA0, SB0, SWv0, SWe0, ns0, nb0;
    {
        int idx = i0 * N_ + lane;
        float sg = sSig[idx], m = sMu[idx], ww = sW[idx], e = sErev[idx];
        SA0 = -sg * LOG2E; SB0 = m * sg * LOG2E; SWv0 = ww; SWe0 = ww * e;
        ns0 = input_w[i0] / std_us[i0];
        nb0 = input_b[i0] - mean_us[i0] / std_us[i0] * input_w[i0];
    }
    float SA1 = 0.f, SB1 = 0.f, SWv1 = 0.f, SWe1 = 0.f, ns1 = 0.f, nb1 = 0.f;
    if (has1) {
        int idx = i1 * N_ + lane;
        float sg = sSig[idx], m = sMu[idx], ww = sW[idx], e = sErev[idx];
        SA1 = -sg * LOG2E; SB1 = m * sg * LOG2E; SWv1 = ww; SWe1 = ww * e;
        ns1 = input_w[i1] / std_us[i1];
        nb1 = input_b[i1] - mean_us[i1] / std_us[i1] * input_w[i1];
    }

    // --- output consts (lanes 0..2 hold motor columns 0..2) ---
    float OW = 0.f, OB = 0.f;
    if (t < MOT_) {
        OW = output_w[t] * std_us[t];
        OB = output_b[t] * std_us[t] + mean_us[t];
    }

    const float* xb = x + (size_t)b * S_ * IN_;
    float* ob = out + (size_t)b * S_ * MOT_;

    // --- init: v=0, flags=0, step-0 sensory into s_lds[0] ---
    if (t < N_) vbuf[0][t] = 0.f;
    if (t < 8)  vflag[t >> 2][t & 3] = 0;
    {
        float u  = fmaf(xb[i0], ns0, nb0);
        float e  = __builtin_amdgcn_exp2f(fmaf(u, SA0, SB0));
        float sg = __builtin_amdgcn_rcpf(1.0f + e);
        s_lds[0][i0][lane][0] = SWe0 * sg;
        s_lds[0][i0][lane][1] = SWv0 * sg;
        if (has1) {
            float u1  = fmaf(xb[i1], ns1, nb1);
            float e1  = __builtin_amdgcn_exp2f(fmaf(u1, SA1, SB1));
            float sg1 = __builtin_amdgcn_rcpf(1.0f + e1);
            s_lds[0][i1][lane][0] = SWe1 * sg1;
            s_lds[0][i1][lane][1] = SWv1 * sg1;
        }
    }
    __syncthreads();

    float v_my = 0.f;
    int mbase = 0;

    for (int s = 0; s < S_; ++s) {
        // prefetch next step's input; force VMEM (vmcnt) so lgkm waits never
        // touch it
        const int s1 = (s + 1 < S_) ? (s + 1) : s;
        int off0 = s1 * IN_ + i0;
        asm volatile("" : "+v"(off0));
        float xn0 = xb[off0];
        float xn1 = 0.f;
        if (has1) {
            int off1 = s1 * IN_ + i1;
            asm volatile("" : "+v"(off1));
            xn1 = xb[off1];
        }

        const int sp = s & 1;
        // fold sensory + leak into per-step bases (broadcast ds reads)
        float a = 0.f, d = 0.f;
#pragma unroll
        for (int ci = 0; ci < IN_; ++ci) {
            float2 sv = *(const float2*)&s_lds[sp][ci][myCol][0];
            a += sv.x; d += sv.y;
        }
        const float nbs = gv + a;
        const float dbs = dbase + d;

#pragma unroll
        for (int k = 0; k < UNF; ++k) {
            const int par  = k & 1;
            const int need = mbase + k;

            // dataflow wait: all 4 producer flags must reach `need`
            for (;;) {
                int f0 = __hip_atomic_load(&vflag[par][0], __ATOMIC_RELAXED, __HIP_MEMORY_SCOPE_WORKGROUP);
                int f1 = __hip_atomic_load(&vflag[par][1], __ATOMIC_RELAXED, __HIP_MEMORY_SCOPE_WORKGROUP);
                int f2 = __hip_atomic_load(&vflag[par][2], __ATOMIC_RELAXED, __HIP_MEMORY_SCOPE_WORKGROUP);
                int f3 = __hip_atomic_load(&vflag[par][3], __ATOMIC_RELAXED, __HIP_MEMORY_SCOPE_WORKGROUP);
                if (f0 >= need && f1 >= need && f2 >= need && f3 >= need) break;
            }
            asm volatile("" ::: "memory");

            // per-producer-wave phases, compile-time param indexing
            float pnq[4], pdq[4];
#pragma unroll
            for (int q = 0; q < 4; ++q) {
                float4 cv = *(const float4*)&vbuf[par][q * 16 + cc4];
                float c0 = cv.x, c1 = cv.y, c2 = cv.z, c3 = cv.w;
                float e0 = __builtin_amdgcn_exp2f(fmaf(c0, A[q*4+0], Bc[q*4+0]));
                float e1 = __builtin_amdgcn_exp2f(fmaf(c1, A[q*4+1], Bc[q*4+1]));
                float e2 = __builtin_amdgcn_exp2f(fmaf(c2, A[q*4+2], Bc[q*4+2]));
                float e3 = __builtin_amdgcn_exp2f(fmaf(c3, A[q*4+3], Bc[q*4+3]));
                float s0 = __builtin_amdgcn_rcpf(1.0f + e0);
                float s1x = __builtin_amdgcn_rcpf(1.0f + e1);
                float s2 = __builtin_amdgcn_rcpf(1.0f + e2);
                float s3 = __builtin_amdgcn_rcpf(1.0f + e3);
                pnq[q] = fmaf(We[q*4+0], s0, fmaf(We[q*4+1], s1x,
                         fmaf(We[q*4+2], s2, We[q*4+3] * s3)));
                pdq[q] = fmaf(Wr[q*4+0], s0, fmaf(Wr[q*4+1], s1x,
                         fmaf(Wr[q*4+2], s2, Wr[q*4+3] * s3)));
            }
            float pn = (pnq[0] + pnq[1]) + (pnq[2] + pnq[3]);
            float pd = (pdq[0] + pdq[1]) + (pdq[2] + pdq[3]);

            // VALU butterfly over cc (lane bits 4,5): full column sums
            pn = red16(pn);  pd = red16(pd);
            pn = red32(pn);  pd = red32(pd);

            v_my = fmaf(cmt, v_my, nbs + pn) * __builtin_amdgcn_rcpf(dbs + pd);

            // publish v (16 writer lanes, distinct banks) + sensory for s+1
            if (lane < 16) vbuf[par ^ 1][w * 16 + lane] = v_my;

            if (k == 1) {
                float u  = fmaf(xn0, ns0, nb0);
                float e4 = __builtin_amdgcn_exp2f(fmaf(u, SA0, SB0));
                float sg = __builtin_amdgcn_rcpf(1.0f + e4);
                s_lds[sp ^ 1][i0][lane][0] = SWe0 * sg;
                s_lds[sp ^ 1][i0][lane][1] = SWv0 * sg;
                if (has1) {
                    float u1  = fmaf(xn1, ns1, nb1);
                    float e5  = __builtin_amdgcn_exp2f(fmaf(u1, SA1, SB1));
                    float sg1 = __builtin_amdgcn_rcpf(1.0f + e5);
                    s_lds[sp ^ 1][i1][lane][0] = SWe1 * sg1;
                    s_lds[sp ^ 1][i1][lane][1] = SWv1 * sg1;
                }
            }

            // drain own LDS writes, then publish progress
            asm volatile("s_waitcnt lgkmcnt(0)" ::: "memory");
            if (lane == 0)
                __hip_atomic_store(&vflag[par ^ 1][w], need + 1,
                                   __ATOMIC_RELAXED, __HIP_MEMORY_SCOPE_WORKGROUP);
        }
        mbase += UNF;

        // motor outputs: columns 0..2 live in lanes 0..2 of wave 0
        if (t < MOT_) ob[s * MOT_ + t] = fmaf(v_my, OW, OB);
    }
}

extern "C" void kernel_launch(void* const* d_in, const int* in_sizes, int n_in,
                              void* d_out, int out_size, void* d_ws, size_t ws_size,
                              hipStream_t stream) {
    (void)in_sizes; (void)n_in; (void)d_ws; (void)ws_size; (void)out_size;
    const float* x       = (const float*)d_in[0];
    const float* mean_us = (const float*)d_in[1];
    const float* std_us  = (const float*)d_in[2];
    const float* input_w = (const float*)d_in[3];
    const float* input_b = (const float*)d_in[4];
    const float* out_w   = (const float*)d_in[5];
    const float* out_b   = (const float*)d_in[6];
    const float* gleak   = (const float*)d_in[7];
    const float* vleak   = (const float*)d_in[8];
    const float* cm      = (const float*)d_in[9];
    const float* sW      = (const float*)d_in[10];
    const float* sMu     = (const float*)d_in[11];
    const float* sSig    = (const float*)d_in[12];
    const float* sErev   = (const float*)d_in[13];
    const float* W       = (const float*)d_in[14];
    const float* Mu      = (const float*)d_in[15];
    const float* Sig     = (const float*)d_in[16];
    const float* Erev    = (const float*)d_in[17];
    float* out = (float*)d_out;

    ltc_kernel<<<dim3(B_), dim3(256), 0, stream>>>(
        x, mean_us, std_us, input_w, input_b, out_w, out_b,
        gleak, vleak, cm, sW, sMu, sSig, sErev, W, Mu, Sig, Erev, out);
}

// Round 9
// 9186.784 us; speedup vs baseline: 1.3180x; 1.3180x over previous
//
#include <hip/hip_runtime.h>

#define B_ 128
#define S_ 4096
#define IN_ 6
#define N_ 64
#define MOT_ 3
#define UNF 6
#define EPS_ 1e-8f
#define LOG2E 1.4426950408889634f

typedef float v2f __attribute__((ext_vector_type(2)));

// ---- VALU-pipe cross-lane pair-sums over lane bits 4 and 5 ----
__device__ __forceinline__ float red16(float x) {
#if __has_builtin(__builtin_amdgcn_permlane16_swap)
    auto r = __builtin_amdgcn_permlane16_swap(__float_as_int(x), __float_as_int(x),
                                              false, false);
    return __int_as_float((int)r[0]) + __int_as_float((int)r[1]);
#else
    return x + __shfl_xor(x, 16, 64);
#endif
}
__device__ __forceinline__ float red32(float x) {
#if __has_builtin(__builtin_amdgcn_permlane32_swap)
    auto r = __builtin_amdgcn_permlane32_swap(__float_as_int(x), __float_as_int(x),
                                              false, false);
    return __int_as_float((int)r[0]) + __int_as_float((int)r[1]);
#else
    return x + __shfl_xor(x, 32, 64);
#endif
}

// barrier with LDS-only drain (no vmcnt: global loads/stores stay in flight)
__device__ __forceinline__ void lds_barrier() {
    asm volatile("s_waitcnt lgkmcnt(0)" ::: "memory");
    __builtin_amdgcn_s_barrier();
}

// One workgroup per batch chain. 256 threads = 4 waves = 1 wave/SIMD.
// Wave w owns columns w*16..w*16+15; lane l = (cc=l>>4 j-chunk of 16, ii=l&15
// col). Per unfold: 16 sigmoids/lane with PACKED-f32 arg/add math, split
// accumulators, 2-stage VALU butterfly (permlane16/32_swap), ONE lgkm-only
// barrier. Sensory synapses are computed PER-LANE in registers at step start
// (no sensory LDS, no divergent block in the k-loop; all waves uniform).
__launch_bounds__(256, 1)
__global__ void ltc_kernel(
    const float* __restrict__ x,
    const float* __restrict__ mean_us, const float* __restrict__ std_us,
    const float* __restrict__ input_w, const float* __restrict__ input_b,
    const float* __restrict__ output_w, const float* __restrict__ output_b,
    const float* __restrict__ gleak, const float* __restrict__ vleak,
    const float* __restrict__ cm,
    const float* __restrict__ sW, const float* __restrict__ sMu,
    const float* __restrict__ sSig, const float* __restrict__ sErev,
    const float* __restrict__ W, const float* __restrict__ Mu,
    const float* __restrict__ Sig, const float* __restrict__ Erev,
    float* __restrict__ out)
{
    const int b    = blockIdx.x;
    const int t    = threadIdx.x;
    const int lane = t & 63;
    const int w    = t >> 6;      // wave 0..3
    const int cc   = lane >> 4;   // j-chunk 0..3 (16 j's each)
    const int ii   = lane & 15;   // column within wave's block
    const int myCol = w * 16 + ii;
    const int jb   = cc * 16;

    __shared__ __align__(16) float vbuf[2][N_];

    // --- recurrent synapse params: 16 synapses (j=jb..jb+15) of column myCol,
    // packed in pairs for v_pk_fma: sigmoid((v-mu)*sig) = 1/(1+exp2(v*A + Bc))
    v2f A2[8], B2[8];
    float Wr[16], We[16];
#pragma unroll
    for (int jj = 0; jj < 16; ++jj) {
        int idx = (jb + jj) * N_ + myCol;
        float sg = Sig[idx], m = Mu[idx], ww = W[idx], e = Erev[idx];
        A2[jj >> 1][jj & 1] = -sg * LOG2E;
        B2[jj >> 1][jj & 1] = m * sg * LOG2E;
        Wr[jj] = ww;
        We[jj] = ww * e;
    }

    // --- per-column state consts ---
    const float cmt = cm[myCol] * (float)UNF;
    const float glk = gleak[myCol];
    const float gv  = glk * vleak[myCol];
    const float dbase = cmt + glk + EPS_;

    // --- sensory params: per-lane, ALL 6 inputs for column myCol ---
    float SA[IN_], SB[IN_], SWe[IN_], SWv[IN_], NS[IN_], NB[IN_];
#pragma unroll
    for (int ci = 0; ci < IN_; ++ci) {
        int idx = ci * N_ + myCol;
        float sg = sSig[idx], m = sMu[idx], ww = sW[idx], e = sErev[idx];
        SA[ci]  = -sg * LOG2E;
        SB[ci]  = m * sg * LOG2E;
        SWv[ci] = ww;
        SWe[ci] = ww * e;
        NS[ci]  = input_w[ci] / std_us[ci];
        NB[ci]  = input_b[ci] - mean_us[ci] / std_us[ci] * input_w[ci];
    }

    // --- output consts (lanes 0..2 of wave 0 hold motor columns 0..2) ---
    float OW = 0.f, OB = 0.f;
    if (t < MOT_) {
        OW = output_w[t] * std_us[t];
        OB = output_b[t] * std_us[t] + mean_us[t];
    }

    const float* xb = x + (size_t)b * S_ * IN_;
    float* ob = out + (size_t)b * S_ * MOT_;

    if (t < N_) vbuf[0][t] = 0.f;

    // step-0 inputs (blocking, one-time); force VMEM via VGPR offset
    float xc[IN_];
    {
        int off = 0;
        asm volatile("" : "+v"(off));
        float2 x01 = *(const float2*)(xb + off);
        float2 x23 = *(const float2*)(xb + off + 2);
        float2 x45 = *(const float2*)(xb + off + 4);
        xc[0] = x01.x; xc[1] = x01.y; xc[2] = x23.x;
        xc[3] = x23.y; xc[4] = x45.x; xc[5] = x45.y;
    }
    __syncthreads();

    float v_my = 0.f;

    for (int s = 0; s < S_; ++s) {
        // prefetch next step's inputs (VMEM, stays in flight across lgkm waits)
        const int s1 = (s + 1 < S_) ? (s + 1) : s;
        int off = s1 * IN_;
        asm volatile("" : "+v"(off));
        float2 p01 = *(const float2*)(xb + off);
        float2 p23 = *(const float2*)(xb + off + 2);
        float2 p45 = *(const float2*)(xb + off + 4);

        // per-lane sensory fold for this step (registers only; overlaps k=0's
        // v-read + sigmoid phase, consumed only after k=0's butterfly)
        float wns = 0.f, wds = 0.f;
#pragma unroll
        for (int ci = 0; ci < IN_; ++ci) {
            float u  = fmaf(xc[ci], NS[ci], NB[ci]);
            float e  = __builtin_amdgcn_exp2f(fmaf(u, SA[ci], SB[ci]));
            float sg = __builtin_amdgcn_rcpf(1.0f + e);
            wns = fmaf(SWe[ci], sg, wns);
            wds = fmaf(SWv[ci], sg, wds);
        }
        const float nbs = gv + wns;
        const float dbs = dbase + wds;

#pragma unroll
        for (int k = 0; k < UNF; ++k) {
            const int p = k & 1;
            // broadcast-read the 16 v's of this lane's j-chunk (4x ds_read_b128)
            float4 q0 = *(const float4*)&vbuf[p][jb];
            float4 q1 = *(const float4*)&vbuf[p][jb + 4];
            float4 q2 = *(const float4*)&vbuf[p][jb + 8];
            float4 q3 = *(const float4*)&vbuf[p][jb + 12];
            const v2f vp[8] = {
                {q0.x, q0.y}, {q0.z, q0.w}, {q1.x, q1.y}, {q1.z, q1.w},
                {q2.x, q2.y}, {q2.z, q2.w}, {q3.x, q3.y}, {q3.z, q3.w}};

            float pn0 = 0.f, pd0 = 0.f, pn1 = 0.f, pd1 = 0.f;
#pragma unroll
            for (int pi = 0; pi < 8; ++pi) {
                v2f z  = __builtin_elementwise_fma(vp[pi], A2[pi], B2[pi]); // pk_fma
                v2f e  = {__builtin_amdgcn_exp2f(z.x), __builtin_amdgcn_exp2f(z.y)};
                v2f tt = e + 1.0f;                                          // pk_add
                float s0 = __builtin_amdgcn_rcpf(tt.x);
                float s1x = __builtin_amdgcn_rcpf(tt.y);
                pn0 = fmaf(We[2*pi],   s0,  pn0);
                pd0 = fmaf(Wr[2*pi],   s0,  pd0);
                pn1 = fmaf(We[2*pi+1], s1x, pn1);
                pd1 = fmaf(Wr[2*pi+1], s1x, pd1);
            }
            float pn = pn0 + pn1;
            float pd = pd0 + pd1;

            // VALU butterfly over cc (lane bits 4,5): full column sums
            pn = red16(pn);  pd = red16(pd);
            pn = red32(pn);  pd = red32(pd);

            v_my = fmaf(cmt, v_my, nbs + pn) * __builtin_amdgcn_rcpf(dbs + pd);

            // publish v for next unfold (double-buffered, one writer per column)
            if (lane < 16) vbuf[p ^ 1][w * 16 + lane] = v_my;

            lds_barrier();
        }

        // rotate prefetched inputs; motor outputs from lanes 0..2 of wave 0
        xc[0] = p01.x; xc[1] = p01.y; xc[2] = p23.x;
        xc[3] = p23.y; xc[4] = p45.x; xc[5] = p45.y;
        if (t < MOT_) ob[s * MOT_ + t] = fmaf(v_my, OW, OB);
    }
}

extern "C" void kernel_launch(void* const* d_in, const int* in_sizes, int n_in,
                              void* d_out, int out_size, void* d_ws, size_t ws_size,
                              hipStream_t stream) {
    (void)in_sizes; (void)n_in; (void)d_ws; (void)ws_size; (void)out_size;
    const float* x       = (const float*)d_in[0];
    const float* mean_us = (const float*)d_in[1];
    const float* std_us  = (const float*)d_in[2];
    const float* input_w = (const float*)d_in[3];
    const float* input_b = (const float*)d_in[4];
    const float* out_w   = (const float*)d_in[5];
    const float* out_b   = (const float*)d_in[6];
    const float* gleak   = (const float*)d_in[7];
    const float* vleak   = (const float*)d_in[8];
    const float* cm      = (const float*)d_in[9];
    const float* sW      = (const float*)d_in[10];
    const float* sMu     = (const float*)d_in[11];
    const float* sSig    = (const float*)d_in[12];
    const float* sErev   = (const float*)d_in[13];
    const float* W       = (const float*)d_in[14];
    const float* Mu      = (const float*)d_in[15];
    const float* Sig     = (const float*)d_in[16];
    const float* Erev    = (const float*)d_in[17];
    float* out = (float*)d_out;

    ltc_kernel<<<dim3(B_), dim3(256), 0, stream>>>(
        x, mean_us, std_us, input_w, input_b, out_w, out_b,
        gleak, vleak, cm, sW, sMu, sSig, sErev, W, Mu, Sig, Erev, out);
}